// Round 4
// baseline (451.391 us; speedup 1.0000x reference)
//
#include <hip/hip_runtime.h>
#include <math.h>

#define Hn 1024
#define Dn 256
#define Bn 8
#define DTf 0.125f

constexpr float kA[6][5] = {
  {0.f, 0.f, 0.f, 0.f, 0.f},
  {1.0f/5.0f, 0.f, 0.f, 0.f, 0.f},
  {3.0f/40.0f, 9.0f/40.0f, 0.f, 0.f, 0.f},
  {44.0f/45.0f, -56.0f/15.0f, 32.0f/9.0f, 0.f, 0.f},
  {19372.0f/6561.0f, -25360.0f/2187.0f, 64448.0f/6561.0f, -212.0f/729.0f, 0.f},
  {9017.0f/3168.0f, -355.0f/33.0f, 46732.0f/5247.0f, 49.0f/176.0f, -5103.0f/18656.0f}
};
constexpr float kC[6] = {0.f, 0.2f, 0.3f, 0.8f, 8.0f/9.0f, 1.0f};
constexpr float kBW[6] = {35.0f/384.0f, 0.f, 500.0f/1113.0f, 125.0f/192.0f,
                          -2187.0f/6784.0f, 11.0f/84.0f};

__device__ __forceinline__ float fast_tanh(float x) {
  const float ax = fabsf(x);
  const float z = __expf(-2.0f * ax);
  const float t = (1.0f - z) * __builtin_amdgcn_rcpf(1.0f + z);
  return copysignf(t, x);
}

// row permutation: spreads the 4 simultaneous ks-groups across bank quads
__device__ __forceinline__ int prow(int e) { return e ^ ((e >> 5) & 7); }

// ---------------- merged precompute ----------------
// wg 0..255: M=(W1^T W1).*(W2 W2^T) row-permuted; wg 256..511: Z=W2@W1 row-permuted;
// wg 512: zero scal/flags; 513..516: cc; 517..520: bz; 521..524: W2p (row-permuted copy)
__global__ __launch_bounds__(256) void precomp(
    const float* __restrict__ W1, const float* __restrict__ W2,
    const float* __restrict__ b2,
    float* __restrict__ Mm, float* __restrict__ Zz, float* __restrict__ W2p,
    float* __restrict__ cc, float* __restrict__ bz, float* __restrict__ scal,
    unsigned* __restrict__ flags) {
  __shared__ float sm[8704];
  const int tid = threadIdx.x;
  const int wg = blockIdx.x;
  if (wg < 256) {
    float* a1k  = sm;            // [32][64]
    float* a1l  = sm + 2048;     // [32][64]
    float* w2kT = sm + 4096;     // [32][72]
    float* w2lT = sm + 6400;     // [32][72]
    const int k0 = (wg & 15) * 64, l0 = (wg >> 4) * 64;
    const int kq = tid & 15, lq = tid >> 4;
    float g1[4][4] = {}, g2[4][4] = {};
    for (int dc = 0; dc < 8; dc++) {
      const int d0 = dc * 32;
      __syncthreads();
      for (int idx = tid; idx < 2048; idx += 256) {
        const int r1 = idx >> 6, c1 = idx & 63;
        a1k[r1 * 64 + c1] = W1[(d0 + r1) * Hn + k0 + c1];
        a1l[r1 * 64 + c1] = W1[(d0 + r1) * Hn + l0 + c1];
      }
      for (int idx = tid; idx < 2048; idx += 256) {
        const int r1 = idx >> 5, c1 = idx & 31;
        w2kT[c1 * 72 + r1] = W2[(k0 + r1) * Dn + d0 + c1];
        w2lT[c1 * 72 + r1] = W2[(l0 + r1) * Dn + d0 + c1];
      }
      __syncthreads();
      #pragma unroll 4
      for (int dd = 0; dd < 32; dd++) {
        const float4 ak = *(const float4*)&a1k[dd * 64 + kq * 4];
        const float4 al = *(const float4*)&a1l[dd * 64 + lq * 4];
        const float4 wk = *(const float4*)&w2kT[dd * 72 + kq * 4];
        const float4 wl = *(const float4*)&w2lT[dd * 72 + lq * 4];
        const float akv[4] = {ak.x, ak.y, ak.z, ak.w};
        const float alv[4] = {al.x, al.y, al.z, al.w};
        const float wkv[4] = {wk.x, wk.y, wk.z, wk.w};
        const float wlv[4] = {wl.x, wl.y, wl.z, wl.w};
        #pragma unroll
        for (int i = 0; i < 4; i++)
          #pragma unroll
          for (int j = 0; j < 4; j++) {
            g1[i][j] += akv[i] * alv[j];
            g2[i][j] += wkv[i] * wlv[j];
          }
      }
    }
    #pragma unroll
    for (int i = 0; i < 4; i++)
      #pragma unroll
      for (int j = 0; j < 4; j++)
        Mm[prow(k0 + kq * 4 + i) * Hn + l0 + lq * 4 + j] = g1[i][j] * g2[i][j];
  } else if (wg < 512) {
    float* w2lT = sm;            // [64][72]
    float* w1t  = sm + 4608;     // [64][64]
    const int bw = wg - 256;
    const int e0 = (bw & 15) * 64, l0 = (bw >> 4) * 64;
    const int eq = tid & 15, lq = tid >> 4;
    float acc[4][4] = {};
    for (int dc = 0; dc < 4; dc++) {
      const int d0 = dc * 64;
      __syncthreads();
      for (int idx = tid; idx < 4096; idx += 256) {
        const int r1 = idx >> 6, c1 = idx & 63;
        w2lT[c1 * 72 + r1] = W2[(l0 + r1) * Dn + d0 + c1];
        w1t[r1 * 64 + c1] = W1[(d0 + r1) * Hn + e0 + c1];
      }
      __syncthreads();
      #pragma unroll 4
      for (int dd = 0; dd < 64; dd++) {
        const float4 wv = *(const float4*)&w2lT[dd * 72 + lq * 4];
        const float4 xv = *(const float4*)&w1t[dd * 64 + eq * 4];
        const float wvv[4] = {wv.x, wv.y, wv.z, wv.w};
        const float xvv[4] = {xv.x, xv.y, xv.z, xv.w};
        #pragma unroll
        for (int i = 0; i < 4; i++)
          #pragma unroll
          for (int j = 0; j < 4; j++)
            acc[i][j] += wvv[i] * xvv[j];
      }
    }
    #pragma unroll
    for (int i = 0; i < 4; i++)
      #pragma unroll
      for (int j = 0; j < 4; j++)
        Zz[prow(l0 + lq * 4 + i) * Hn + e0 + eq * 4 + j] = acc[i][j];
  } else if (wg == 512) {
    if (tid < 64) scal[tid] = 0.f;
    if (tid < 33) flags[tid] = 0u;
  } else if (wg < 517) {
    const int k = (wg - 513) * 256 + tid;
    float s = 0.f;
    for (int d = 0; d < Dn; d++) s += W1[d * Hn + k] * W2[k * Dn + d];
    cc[k] = s;
  } else if (wg < 521) {
    const int e = (wg - 517) * 256 + tid;
    float s = 0.f;
    for (int d = 0; d < Dn; d++) s += b2[d] * W1[d * Hn + e];
    bz[e] = s;
  } else {
    const int base = (wg - 521) * 256;
    for (int idx = tid; idx < 16384; idx += 256) {
      const int r = base + (idx >> 6), c4 = (idx & 63) * 4;
      const float4 v = *(const float4*)&W2[r * Dn + c4];
      *(float4*)&W2p[prow(r) * Dn + c4] = v;
    }
  }
}

// ---------------- persistent main ----------------
// wg 0..31:  G (produces h; the only synchronized group)
// wg 32..39: K (k = h@W2p -> z, kl, vfn)   wg 40..71: R (M@s -> jfn, trJ)
__global__ __launch_bounds__(512) void ode_main(
    const float* __restrict__ x0, const float* __restrict__ W1,
    const float* __restrict__ b1, const float* __restrict__ wt,
    const float* __restrict__ b2, const float* __restrict__ mu,
    float* __restrict__ out,
    const float* __restrict__ Mm, const float* __restrict__ Zz,
    const float* __restrict__ W2p,
    const float* __restrict__ cc, const float* __restrict__ bz,
    float* __restrict__ hbuf, float* __restrict__ scal,
    unsigned* __restrict__ flags) {
  __shared__ float hv[Hn][4];        // physical row p holds h[p(p_row)] (or s for R)
  __shared__ float red2[8][16][17];
  __shared__ float swr[4][4][2];
  __shared__ float x0g[4][260];
  __shared__ int aldc;

  const int tid = threadIdx.x;
  const int wg = blockIdx.x;
  int role, cb, sh;
  if (wg < 32) { role = 0; cb = wg >> 1; sh = wg & 1; }
  else if (wg < 40) { role = 2; cb = (wg - 32) >> 1; sh = (wg - 32) & 1; }
  else { role = 1; cb = (wg - 40) >> 1; sh = (wg - 40) & 1; }
  const int c0 = cb * 64;
  unsigned* f16 = flags + sh * 16;
  const int co = tid >> 2, b4 = tid & 3, bglob = sh * 4 + b4;
  const int wv = tid >> 6, lane = tid & 63;
  const int cq = lane & 15, ks = tid >> 4;

  if (tid == 0) aldc = 0;

  float ubr = 0.f, xbr = 0.f;
  float gkr[6] = {}, kr[6] = {};
  float b1c = 0.f, wtc = 0.f, bzc = 0.f, ccr = 0.f, b2c = 0.f, muc = 0.f;
  int pco = 0;

  // ---- prologue ----
  if (role == 0) {
    for (int idx = tid; idx < 1024; idx += 512)
      x0g[idx >> 8][idx & 255] = x0[(sh * 4 + (idx >> 8)) * Dn + (idx & 255)];
    __syncthreads();
    if (tid < 256) {
      const int col = c0 + co;
      b1c = b1[col]; wtc = wt[col]; bzc = bz[col];
      float ub = 0.f;
      for (int d = 0; d < Dn; ++d) ub += x0g[b4][d] * W1[d * Hn + col];
      ubr = ub;
      const float h0 = fast_tanh(ubr + b1c);
      __hip_atomic_store(&hbuf[sh * 4096 + cb * 256 + tid], h0,
                         __ATOMIC_RELAXED, __HIP_MEMORY_SCOPE_AGENT);
    }
    asm volatile("s_waitcnt vmcnt(0)" ::: "memory");
    if (tid < 256 && lane == 0) {
      const int old = atomicAdd(&aldc, 1);
      if ((old & 3) == 3)
        __hip_atomic_store(&f16[cb], 1u, __ATOMIC_RELAXED, __HIP_MEMORY_SCOPE_AGENT);
    }
  } else if (role == 2) {
    if (tid < 256) {
      const int d = c0 + co;
      xbr = x0[bglob * Dn + d];
      muc = mu[d]; b2c = b2[d];
      float v = xbr * xbr;
      v += __shfl_xor(v, 4, 64);
      v += __shfl_xor(v, 8, 64);
      v += __shfl_xor(v, 16, 64);
      v += __shfl_xor(v, 32, 64);
      if (lane < 4) swr[wv][lane][0] = v;
    }
    __syncthreads();
    if (tid < 4) {
      const float s = swr[0][tid][0] + swr[1][tid][0] + swr[2][tid][0] + swr[3][tid][0];
      atomicAdd(&scal[(sh * 4 + tid) * 8 + 4], s);
    }
  } else {
    if (tid < 256) { ccr = cc[c0 + co]; pco = prow(c0 + co); }
  }

  const float* Mat = (role == 0) ? Zz : (role == 1) ? Mm : W2p;
  const int ldm = (role == 2) ? Dn : Hn;
  float acc_a = 0.f, acc_b = 0.f;

  for (int n = 0; n < 8; ++n) {
    #pragma unroll
    for (int i = 0; i < 6; ++i) {
      if (role == 1 && i == 1) continue;       // BW[1]==0: R output unused
      if (role == 0 && n == 7 && i == 5) break; // G: stage 47 feeds nothing
      const int s = n * 6 + i;

      // ---- per-wave: poll + load own 2 chunks (no WG barrier) ----
      const float* hsrc = hbuf + (size_t)(s * 2 + sh) * 4096;
      #pragma unroll
      for (int cc2 = 0; cc2 < 2; ++cc2) {
        const int ch = 2 * wv + cc2;
        unsigned v = __hip_atomic_load(&f16[ch], __ATOMIC_RELAXED,
                                       __HIP_MEMORY_SCOPE_AGENT);
        while (v < (unsigned)(s + 1)) {
          __builtin_amdgcn_s_sleep(1);
          v = __hip_atomic_load(&f16[ch], __ATOMIC_RELAXED,
                                __HIP_MEMORY_SCOPE_AGENT);
        }
        asm volatile("" ::: "memory");
        float4 hval = *(const float4*)&hsrc[ch * 256 + lane * 4];
        if (role == 1) {
          hval.x = 1.f - hval.x * hval.x;
          hval.y = 1.f - hval.y * hval.y;
          hval.z = 1.f - hval.z * hval.z;
          hval.w = 1.f - hval.w * hval.w;
        }
        *(float4*)&hv[prow(ch * 64 + lane)][0] = hval;
      }
      __builtin_amdgcn_sched_barrier(0);

      // ---- matvec over own K range (linear physical rows, conflict-free) ----
      {
        const float* mp = Mat + (ks * 32) * ldm + (c0 + cq * 4);
        float acc[4][4] = {};
        #pragma unroll 4
        for (int l = 0; l < 32; ++l) {
          const float4 mv = *(const float4*)mp;
          const float4 hb = *(const float4*)&hv[ks * 32 + l][0];
          const float mvv[4] = {mv.x, mv.y, mv.z, mv.w};
          const float hbv[4] = {hb.x, hb.y, hb.z, hb.w};
          #pragma unroll
          for (int c2 = 0; c2 < 4; c2++)
            #pragma unroll
            for (int bb = 0; bb < 4; bb++)
              acc[c2][bb] += mvv[c2] * hbv[bb];
          mp += ldm;
        }
        #pragma unroll
        for (int c2 = 0; c2 < 4; c2++)
          #pragma unroll
          for (int bb = 0; bb < 4; bb++) {
            acc[c2][bb] += __shfl_xor(acc[c2][bb], 16, 64);
            acc[c2][bb] += __shfl_xor(acc[c2][bb], 32, 64);
          }
        if (lane < 16) {
          #pragma unroll
          for (int c2 = 0; c2 < 4; c2++)
            #pragma unroll
            for (int bb = 0; bb < 4; bb++)
              red2[wv][cq][c2 * 4 + bb] = acc[c2][bb];
        }
      }
      __syncthreads();   // barrier(1): red2 complete

      // ---- reduce + role epilogue (waves 0-3) ----
      float hn = 0.f;
      if (tid < 256) {
        const int cq2 = co >> 2, c2 = co & 3;
        float r = 0.f;
        #pragma unroll
        for (int w = 0; w < 8; ++w) r += red2[w][cq2][c2 * 4 + b4];
        if (role == 0) {
          gkr[i] = r + bzc;
          float u;
          if (i == 5) {
            ubr += DTf * (kBW[0] * gkr[0] + kBW[2] * gkr[2] + kBW[3] * gkr[3] +
                          kBW[4] * gkr[4] + kBW[5] * gkr[5]);
            u = ubr + b1c + wtc * ((float)(n + 1) * DTf);
          } else {
            u = ubr + b1c + wtc * (((float)n + kC[i + 1]) * DTf);
            #pragma unroll
            for (int j = 0; j <= i; ++j) u += DTf * kA[i + 1][j] * gkr[j];
          }
          hn = fast_tanh(u);
        } else {
          float v1, v2;
          if (role == 1) {
            const float sv = hv[pco][b4];
            v1 = sv * r;            // -> jfn
            v2 = sv * ccr;          // -> tr(J)
          } else {
            const float kv = r + b2c;
            kr[i] = kv;
            float xi = xbr;
            #pragma unroll
            for (int j = 0; j < i; ++j) xi += DTf * kA[i][j] * kr[j];
            v1 = (xi - muc) * kv;   // -> kl
            v2 = kv * kv;           // -> vfn
          }
          v1 += __shfl_xor(v1, 4, 64);  v2 += __shfl_xor(v2, 4, 64);
          v1 += __shfl_xor(v1, 8, 64);  v2 += __shfl_xor(v2, 8, 64);
          v1 += __shfl_xor(v1, 16, 64); v2 += __shfl_xor(v2, 16, 64);
          v1 += __shfl_xor(v1, 32, 64); v2 += __shfl_xor(v2, 32, 64);
          if (lane < 4) { swr[wv][lane][0] = v1; swr[wv][lane][1] = v2; }
        }
      }
      __syncthreads();   // barrier(2): epilogue reads done, swr complete

      if (role == 0) {
        // publish h[s+1] + flag — outside barriers, per-wave ordering only
        if (tid < 256)
          __hip_atomic_store(&hbuf[(size_t)((s + 1) * 2 + sh) * 4096 + cb * 256 + tid],
                             hn, __ATOMIC_RELAXED, __HIP_MEMORY_SCOPE_AGENT);
        asm volatile("s_waitcnt vmcnt(0)" ::: "memory");
        if (tid < 256 && lane == 0) {
          const int old = atomicAdd(&aldc, 1);
          if ((old & 3) == 3)
            __hip_atomic_store(&f16[cb], (unsigned)(s + 2), __ATOMIC_RELAXED,
                               __HIP_MEMORY_SCOPE_AGENT);
        }
      } else {
        if (tid < 4) {
          const float s1 = swr[0][tid][0] + swr[1][tid][0] + swr[2][tid][0] + swr[3][tid][0];
          const float s2 = swr[0][tid][1] + swr[1][tid][1] + swr[2][tid][1] + swr[3][tid][1];
          const float wgt = DTf * kBW[i];
          if (role == 1) { acc_a += -wgt * s2; acc_b += wgt * s1; }  // trJ, jfn
          else           { acc_a +=  wgt * s1; acc_b += wgt * s2; }  // kl, vfn
        }
        if (role == 2 && i == 5 && tid < 256)
          xbr += DTf * (kBW[0] * kr[0] + kBW[2] * kr[2] + kBW[3] * kr[3] +
                        kBW[4] * kr[4] + kBW[5] * kr[5]);
      }
    }
  }

  // ---- finalize ----
  if (role == 1) {
    if (tid < 4) {
      atomicAdd(&scal[(sh * 4 + tid) * 8 + 0], acc_a);
      atomicAdd(&scal[(sh * 4 + tid) * 8 + 3], acc_b);
    }
  } else if (role == 2) {
    if (tid < 256) out[bglob * 260 + c0 + co] = xbr;
    if (tid < 4) {
      atomicAdd(&scal[(sh * 4 + tid) * 8 + 1], acc_a);
      atomicAdd(&scal[(sh * 4 + tid) * 8 + 2], acc_b);
    }
  }
  if (role != 0) {
    __syncthreads();
    if (tid == 0) {
      asm volatile("s_waitcnt vmcnt(0)" ::: "memory");
      const unsigned old = __hip_atomic_fetch_add(&flags[32], 1u, __ATOMIC_RELAXED,
                                                  __HIP_MEMORY_SCOPE_AGENT);
      if (old == 39u) {
        for (int b = 0; b < Bn; ++b) {
          const float trj = __hip_atomic_load(&scal[b * 8 + 0], __ATOMIC_RELAXED, __HIP_MEMORY_SCOPE_AGENT);
          const float kl  = __hip_atomic_load(&scal[b * 8 + 1], __ATOMIC_RELAXED, __HIP_MEMORY_SCOPE_AGENT);
          const float vfn = __hip_atomic_load(&scal[b * 8 + 2], __ATOMIC_RELAXED, __HIP_MEMORY_SCOPE_AGENT);
          const float jfn = __hip_atomic_load(&scal[b * 8 + 3], __ATOMIC_RELAXED, __HIP_MEMORY_SCOPE_AGENT);
          const float xsq = __hip_atomic_load(&scal[b * 8 + 4], __ATOMIC_RELAXED, __HIP_MEMORY_SCOPE_AGENT);
          out[b * 260 + 256] = -0.5f * (470.49652900079245f + xsq) + trj;
          out[b * 260 + 257] = kl;
          out[b * 260 + 258] = vfn;
          out[b * 260 + 259] = jfn;
        }
      }
    }
  }
}

extern "C" void kernel_launch(void* const* d_in, const int* in_sizes, int n_in,
                              void* d_out, int out_size, void* d_ws, size_t ws_size,
                              hipStream_t stream) {
  (void)in_sizes; (void)n_in; (void)out_size; (void)ws_size;
  const float* x0 = (const float*)d_in[0];
  const float* W1 = (const float*)d_in[1];
  const float* b1 = (const float*)d_in[2];
  const float* wt = (const float*)d_in[3];
  const float* W2 = (const float*)d_in[4];
  const float* b2 = (const float*)d_in[5];
  const float* mu = (const float*)d_in[6];
  float* out = (float*)d_out;
  float* w = (float*)d_ws;

  float* Mm   = w;                  // 1048576
  float* Zz   = Mm + 1048576;       // 1048576
  float* W2p  = Zz + 1048576;       // 262144
  float* cc   = W2p + 262144;       // 1024
  float* bz   = cc + 1024;          // 1024
  float* hbuf = bz + 1024;          // 48*8192 = 393216
  float* scal = hbuf + 393216;      // 64
  unsigned* flags = (unsigned*)(scal + 64);  // 32 chunk flags + done counter

  precomp<<<dim3(525), dim3(256), 0, stream>>>(W1, W2, b2, Mm, Zz, W2p, cc, bz,
                                               scal, flags);
  ode_main<<<dim3(72), dim3(512), 0, stream>>>(x0, W1, b1, wt, b2, mu, out,
                                               Mm, Zz, W2p, cc, bz, hbuf, scal,
                                               flags);
}

// Round 5
// 440.567 us; speedup vs baseline: 1.0246x; 1.0246x over previous
//
#include <hip/hip_runtime.h>
#include <math.h>

#define Hn 1024
#define Dn 256
#define Bn 8
#define DTf 0.125f

constexpr float kA[6][5] = {
  {0.f, 0.f, 0.f, 0.f, 0.f},
  {1.0f/5.0f, 0.f, 0.f, 0.f, 0.f},
  {3.0f/40.0f, 9.0f/40.0f, 0.f, 0.f, 0.f},
  {44.0f/45.0f, -56.0f/15.0f, 32.0f/9.0f, 0.f, 0.f},
  {19372.0f/6561.0f, -25360.0f/2187.0f, 64448.0f/6561.0f, -212.0f/729.0f, 0.f},
  {9017.0f/3168.0f, -355.0f/33.0f, 46732.0f/5247.0f, 49.0f/176.0f, -5103.0f/18656.0f}
};
constexpr float kC[6] = {0.f, 0.2f, 0.3f, 0.8f, 8.0f/9.0f, 1.0f};
constexpr float kBW[6] = {35.0f/384.0f, 0.f, 500.0f/1113.0f, 125.0f/192.0f,
                          -2187.0f/6784.0f, 11.0f/84.0f};

__device__ __forceinline__ float fast_tanh(float x) {
  const float ax = fabsf(x);
  const float z = __expf(-2.0f * ax);
  const float t = (1.0f - z) * __builtin_amdgcn_rcpf(1.0f + z);
  return copysignf(t, x);
}

// ---------------- precompute ----------------
// wg 0..255: M = (W1^T W1) .* (W2 W2^T)   [k][l] linear
// wg 256..511: Z = W2@W1                  [l][e] linear
// wg 512: zero flags/scal; 513..516: cc; 517..520: bz; 521..552: ux = x0@W1
__global__ __launch_bounds__(256) void precomp(
    const float* __restrict__ W1, const float* __restrict__ W2,
    const float* __restrict__ b2, const float* __restrict__ x0,
    float* __restrict__ Mm, float* __restrict__ Zz, float* __restrict__ cc,
    float* __restrict__ bz, float* __restrict__ ux, float* __restrict__ scal,
    unsigned* __restrict__ flags) {
  __shared__ float sm[8704];
  const int tid = threadIdx.x;
  const int wg = blockIdx.x;
  if (wg < 256) {
    float* a1k  = sm;            // [32][64]
    float* a1l  = sm + 2048;     // [32][64]
    float* w2kT = sm + 4096;     // [32][72]
    float* w2lT = sm + 6400;     // [32][72]
    const int k0 = (wg & 15) * 64, l0 = (wg >> 4) * 64;
    const int kq = tid & 15, lq = tid >> 4;
    float g1[4][4] = {}, g2[4][4] = {};
    for (int dc = 0; dc < 8; dc++) {
      const int d0 = dc * 32;
      __syncthreads();
      for (int idx = tid; idx < 2048; idx += 256) {
        const int r1 = idx >> 6, c1 = idx & 63;
        a1k[r1 * 64 + c1] = W1[(d0 + r1) * Hn + k0 + c1];
        a1l[r1 * 64 + c1] = W1[(d0 + r1) * Hn + l0 + c1];
      }
      for (int idx = tid; idx < 2048; idx += 256) {
        const int r1 = idx >> 5, c1 = idx & 31;
        w2kT[c1 * 72 + r1] = W2[(k0 + r1) * Dn + d0 + c1];
        w2lT[c1 * 72 + r1] = W2[(l0 + r1) * Dn + d0 + c1];
      }
      __syncthreads();
      #pragma unroll 4
      for (int dd = 0; dd < 32; dd++) {
        const float4 ak = *(const float4*)&a1k[dd * 64 + kq * 4];
        const float4 al = *(const float4*)&a1l[dd * 64 + lq * 4];
        const float4 wk = *(const float4*)&w2kT[dd * 72 + kq * 4];
        const float4 wl = *(const float4*)&w2lT[dd * 72 + lq * 4];
        const float akv[4] = {ak.x, ak.y, ak.z, ak.w};
        const float alv[4] = {al.x, al.y, al.z, al.w};
        const float wkv[4] = {wk.x, wk.y, wk.z, wk.w};
        const float wlv[4] = {wl.x, wl.y, wl.z, wl.w};
        #pragma unroll
        for (int i = 0; i < 4; i++)
          #pragma unroll
          for (int j = 0; j < 4; j++) {
            g1[i][j] += akv[i] * alv[j];
            g2[i][j] += wkv[i] * wlv[j];
          }
      }
    }
    #pragma unroll
    for (int i = 0; i < 4; i++)
      #pragma unroll
      for (int j = 0; j < 4; j++)
        Mm[(k0 + kq * 4 + i) * Hn + l0 + lq * 4 + j] = g1[i][j] * g2[i][j];
  } else if (wg < 512) {
    float* w2lT = sm;            // [64][72]
    float* w1t  = sm + 4608;     // [64][64]
    const int bw = wg - 256;
    const int e0 = (bw & 15) * 64, l0 = (bw >> 4) * 64;
    const int eq = tid & 15, lq = tid >> 4;
    float acc[4][4] = {};
    for (int dc = 0; dc < 4; dc++) {
      const int d0 = dc * 64;
      __syncthreads();
      for (int idx = tid; idx < 4096; idx += 256) {
        const int r1 = idx >> 6, c1 = idx & 63;
        w2lT[c1 * 72 + r1] = W2[(l0 + r1) * Dn + d0 + c1];
        w1t[r1 * 64 + c1] = W1[(d0 + r1) * Hn + e0 + c1];
      }
      __syncthreads();
      #pragma unroll 4
      for (int dd = 0; dd < 64; dd++) {
        const float4 wv = *(const float4*)&w2lT[dd * 72 + lq * 4];
        const float4 xv = *(const float4*)&w1t[dd * 64 + eq * 4];
        const float wvv[4] = {wv.x, wv.y, wv.z, wv.w};
        const float xvv[4] = {xv.x, xv.y, xv.z, xv.w};
        #pragma unroll
        for (int i = 0; i < 4; i++)
          #pragma unroll
          for (int j = 0; j < 4; j++)
            acc[i][j] += wvv[i] * xvv[j];
      }
    }
    #pragma unroll
    for (int i = 0; i < 4; i++)
      #pragma unroll
      for (int j = 0; j < 4; j++)
        Zz[(l0 + lq * 4 + i) * Hn + e0 + eq * 4 + j] = acc[i][j];
  } else if (wg == 512) {
    for (int q = tid; q < 1025; q += 256) flags[q] = 0u;
    if (tid < 64) scal[tid] = 0.f;
  } else if (wg < 517) {
    const int k = (wg - 513) * 256 + tid;
    float s = 0.f;
    for (int d = 0; d < Dn; d++) s += W1[d * Hn + k] * W2[k * Dn + d];
    cc[k] = s;
  } else if (wg < 521) {
    const int e = (wg - 517) * 256 + tid;
    float s = 0.f;
    for (int d = 0; d < Dn; d++) s += b2[d] * W1[d * Hn + e];
    bz[e] = s;
  } else {
    const int idx = (wg - 521) * 256 + tid;   // 32 wgs: ux[b][e]
    const int b = idx >> 10, e = idx & 1023;
    float s = 0.f;
    for (int d = 0; d < Dn; d++) s += x0[b * Dn + d] * W1[d * Hn + e];
    ux[b * Hn + e] = s;
  }
}

// ---------------- persistent main, LDS-resident operand slices ----------------
// wg 0..63:   G (Z cols [16g,16g+16), 8 samples)   -- sole synchronized group
// wg 64..127: R (M cols)    wg 128..143: K (W2 cols)
__global__ __launch_bounds__(512) void ode_main(
    const float* __restrict__ x0, const float* __restrict__ b1,
    const float* __restrict__ wt, const float* __restrict__ W2g,
    const float* __restrict__ b2, const float* __restrict__ mu,
    float* __restrict__ out,
    const float* __restrict__ Mm, const float* __restrict__ Zz,
    const float* __restrict__ cc, const float* __restrict__ bz,
    const float* __restrict__ ux, float* __restrict__ hbuf,
    float* __restrict__ scal, unsigned* __restrict__ flags) {
  __shared__ float Ms[16 * 1028];    // Mat slice, [c][k], pad 1028
  __shared__ float hsf[8 * 1028];    // h (or 1-h^2 for R), [b][k], pad 1028
  __shared__ float red[2 * 8 * 8 * 20];  // [par][wv][cp][20]
  __shared__ int aldc;

  const int tid = threadIdx.x;
  const int wg = blockIdx.x;
  int role, cidx;
  if (wg < 64) { role = 0; cidx = wg; }
  else if (wg < 128) { role = 1; cidx = wg - 64; }
  else { role = 2; cidx = wg - 128; }
  const int wv = tid >> 6, lane = tid & 63;
  const int cp = lane & 7, ks = lane >> 3;
  const int b = tid >> 4, cl = tid & 15;   // epilogue mapping (tid<128)

  if (tid == 0) aldc = 0;
  __syncthreads();

  float ubr = 0.f, xbr = 0.f;
  float b1c = 0.f, wtc = 0.f, bzc = 0.f, ccr = 0.f, b2c = 0.f, muc = 0.f;
  float gkr[6] = {}, kr[6] = {};
  float acc_a = 0.f, acc_b = 0.f;

  // ---- prologue ----
  if (role == 0) {
    if (tid < 128) {
      const int col = 16 * cidx + cl;
      b1c = b1[col]; wtc = wt[col]; bzc = bz[col];
      ubr = ux[b * Hn + col];
      const float h0 = fast_tanh(ubr + b1c);
      __hip_atomic_store(&hbuf[cidx * 128 + tid], h0, __ATOMIC_RELAXED,
                         __HIP_MEMORY_SCOPE_AGENT);
    }
    asm volatile("s_waitcnt vmcnt(0)" ::: "memory");
    if (tid < 128 && lane == 0) {
      const int old = atomicAdd(&aldc, 1);
      if ((old & 1) == 1)
        __hip_atomic_store(&flags[cidx * 16], 1u, __ATOMIC_RELAXED,
                           __HIP_MEMORY_SCOPE_AGENT);
    }
  } else if (role == 1) {
    if (tid < 128) ccr = cc[16 * cidx + cl];
  } else {
    if (tid < 128) {
      const int d = 16 * cidx + cl;
      xbr = x0[b * Dn + d];
      muc = mu[d]; b2c = b2[d];
      float v = xbr * xbr;
      v += __shfl_xor(v, 1, 64); v += __shfl_xor(v, 2, 64);
      v += __shfl_xor(v, 4, 64); v += __shfl_xor(v, 8, 64);
      if (cl == 0) atomicAdd(&scal[b * 8 + 4], v);
    }
  }

  // ---- stage Mat slice into LDS (transposed [c][k]) ----
  {
    const float* msrc = (role == 0) ? Zz : (role == 1) ? Mm : W2g;
    const int mld = (role == 2) ? Dn : Hn;
    const int cb = 16 * cidx;
    for (int j = 0; j < 32; ++j) {
      const int idx = j * 512 + tid;
      const int l = idx >> 4, c = idx & 15;
      Ms[c * 1028 + l] = msrc[l * mld + cb + c];
    }
  }
  __syncthreads();

  // ---- main loop ----
  for (int n = 0; n < 8; ++n) {
    #pragma unroll
    for (int i = 0; i < 6; ++i) {
      const int s = n * 6 + i;
      if (role == 0 && s == 47) break;    // G: stage 47 feeds nothing
      if (role == 1 && i == 1) continue;  // R: BW[1]==0, output unused
      const int par = s & 1;

      // poll the 8 chunk-flags this wave consumes (padded 64B apart)
      {
        const unsigned tgt = (unsigned)(s + 1);
        unsigned v = tgt;
        while (true) {
          if (lane < 8)
            v = __hip_atomic_load(&flags[(8 * wv + lane) * 16],
                                  __ATOMIC_RELAXED, __HIP_MEMORY_SCOPE_AGENT);
          if (__all((int)(v >= tgt))) break;
          __builtin_amdgcn_s_sleep(2);
        }
      }
      asm volatile("" ::: "memory");
      __builtin_amdgcn_sched_barrier(0);

      // stage h for this wave's K-range (atomic loads bypass L1; wave-private rows)
      {
        const float* hsrc = hbuf + (size_t)s * 8192 + wv * 1024;
        #pragma unroll
        for (int j = 0; j < 16; ++j) {
          float hvv = __hip_atomic_load(&hsrc[j * 64 + lane], __ATOMIC_RELAXED,
                                        __HIP_MEMORY_SCOPE_AGENT);
          if (role == 1) hvv = 1.0f - hvv * hvv;
          const int bb = (j * 4 + (lane >> 4)) & 7;
          const int kk = 128 * wv + 16 * (j >> 1) + (lane & 15);
          hsf[bb * 1028 + kk] = hvv;
        }
      }

      // matvec from LDS: per lane 2 cols x 8 samples, K-blocks {4ks+32j}
      float av[16] = {};
      #pragma unroll
      for (int j = 0; j < 4; ++j) {
        const int kb = 128 * wv + 4 * ks + 32 * j;
        const float4 z0 = *(const float4*)&Ms[(2 * cp) * 1028 + kb];
        const float4 z1 = *(const float4*)&Ms[(2 * cp + 1) * 1028 + kb];
        #pragma unroll
        for (int bb = 0; bb < 8; ++bb) {
          const float4 hb = *(const float4*)&hsf[bb * 1028 + kb];
          av[bb]     += z0.x * hb.x + z0.y * hb.y + z0.z * hb.z + z0.w * hb.w;
          av[8 + bb] += z1.x * hb.x + z1.y * hb.y + z1.z * hb.z + z1.w * hb.w;
        }
      }
      #pragma unroll
      for (int q = 0; q < 16; ++q) {
        av[q] += __shfl_xor(av[q], 8, 64);
        av[q] += __shfl_xor(av[q], 16, 64);
        av[q] += __shfl_xor(av[q], 32, 64);
      }
      if (ks == 0) {
        float* rp = &red[((par * 8 + wv) * 8 + cp) * 20];
        #pragma unroll
        for (int q = 0; q < 8; ++q) { rp[q] = av[q]; rp[8 + q] = av[8 + q]; }
      }
      __syncthreads();   // red complete

      // epilogue (waves 0-1): r[c][b] = sum over 8 waves
      if (tid < 128) {
        float r = 0.f;
        #pragma unroll
        for (int w = 0; w < 8; ++w)
          r += red[((par * 8 + w) * 8 + (cl >> 1)) * 20 + (cl & 1) * 8 + b];
        if (role == 0) {
          gkr[i] = r + bzc;
          float u;
          if (i == 5) {
            ubr += DTf * (kBW[0] * gkr[0] + kBW[2] * gkr[2] + kBW[3] * gkr[3] +
                          kBW[4] * gkr[4] + kBW[5] * gkr[5]);
            u = ubr + b1c + wtc * ((float)(n + 1) * DTf);
          } else {
            u = ubr + b1c + wtc * (((float)n + kC[i + 1]) * DTf);
            #pragma unroll
            for (int j2 = 0; j2 <= i; ++j2) u += DTf * kA[i + 1][j2] * gkr[j2];
          }
          const float hn2 = fast_tanh(u);
          __hip_atomic_store(&hbuf[(size_t)(s + 1) * 8192 + cidx * 128 + tid],
                             hn2, __ATOMIC_RELAXED, __HIP_MEMORY_SCOPE_AGENT);
        } else if (role == 1) {
          const float sv = hsf[b * 1028 + 16 * cidx + cl];  // 1-h^2 at own col
          float v1 = sv * r;        // -> jfn
          float v2 = sv * ccr;      // -> trJ
          v1 += __shfl_xor(v1, 1, 64); v2 += __shfl_xor(v2, 1, 64);
          v1 += __shfl_xor(v1, 2, 64); v2 += __shfl_xor(v2, 2, 64);
          v1 += __shfl_xor(v1, 4, 64); v2 += __shfl_xor(v2, 4, 64);
          v1 += __shfl_xor(v1, 8, 64); v2 += __shfl_xor(v2, 8, 64);
          if (cl == 0) {
            const float wgt = DTf * kBW[i];
            acc_a += -wgt * v2;   // dlogq = -trJ
            acc_b += wgt * v1;    // jfn
          }
        } else {
          const float kv = r + b2c;
          kr[i] = kv;
          float xi = xbr;
          #pragma unroll
          for (int j2 = 0; j2 < i; ++j2) xi += DTf * kA[i][j2] * kr[j2];
          float v1 = (xi - muc) * kv;   // -> kl
          float v2 = kv * kv;           // -> vfn
          v1 += __shfl_xor(v1, 1, 64); v2 += __shfl_xor(v2, 1, 64);
          v1 += __shfl_xor(v1, 2, 64); v2 += __shfl_xor(v2, 2, 64);
          v1 += __shfl_xor(v1, 4, 64); v2 += __shfl_xor(v2, 4, 64);
          v1 += __shfl_xor(v1, 8, 64); v2 += __shfl_xor(v2, 8, 64);
          if (cl == 0) {
            const float wgt = DTf * kBW[i];
            acc_a += wgt * v1;
            acc_b += wgt * v2;
          }
          if (i == 5)
            xbr += DTf * (kBW[0] * kr[0] + kBW[2] * kr[2] + kBW[3] * kr[3] +
                          kBW[4] * kr[4] + kBW[5] * kr[5]);
        }
      }
      if (role == 0) {
        // publish: drain h stores, gate 2 waves, release flag (no 2nd barrier;
        // red is parity-buffered, hsf rows are wave-private)
        asm volatile("s_waitcnt vmcnt(0)" ::: "memory");
        if (tid < 128 && lane == 0) {
          const int old = atomicAdd(&aldc, 1);
          if ((old & 1) == 1)
            __hip_atomic_store(&flags[cidx * 16], (unsigned)(s + 2),
                               __ATOMIC_RELAXED, __HIP_MEMORY_SCOPE_AGENT);
        }
      } else {
        __syncthreads();   // protect hsf (R epilogue reads) before next stage-in
      }
    }
  }

  // ---- finalize ----
  if (role == 1) {
    if (tid < 128 && cl == 0) {
      atomicAdd(&scal[b * 8 + 0], acc_a);
      atomicAdd(&scal[b * 8 + 3], acc_b);
    }
  } else if (role == 2) {
    if (tid < 128) out[b * 260 + 16 * cidx + cl] = xbr;
    if (tid < 128 && cl == 0) {
      atomicAdd(&scal[b * 8 + 1], acc_a);
      atomicAdd(&scal[b * 8 + 2], acc_b);
    }
  }
  if (role != 0) {
    asm volatile("s_waitcnt vmcnt(0)" ::: "memory");
    __syncthreads();
    if (tid == 0) {
      const unsigned old = __hip_atomic_fetch_add(&flags[1024], 1u,
                                                  __ATOMIC_RELAXED,
                                                  __HIP_MEMORY_SCOPE_AGENT);
      if (old == 79u) {   // last of 80 consumers writes the scalar outputs
        for (int bb = 0; bb < Bn; ++bb) {
          const float trj = __hip_atomic_load(&scal[bb * 8 + 0], __ATOMIC_RELAXED, __HIP_MEMORY_SCOPE_AGENT);
          const float kl  = __hip_atomic_load(&scal[bb * 8 + 1], __ATOMIC_RELAXED, __HIP_MEMORY_SCOPE_AGENT);
          const float vfn = __hip_atomic_load(&scal[bb * 8 + 2], __ATOMIC_RELAXED, __HIP_MEMORY_SCOPE_AGENT);
          const float jfn = __hip_atomic_load(&scal[bb * 8 + 3], __ATOMIC_RELAXED, __HIP_MEMORY_SCOPE_AGENT);
          const float xsq = __hip_atomic_load(&scal[bb * 8 + 4], __ATOMIC_RELAXED, __HIP_MEMORY_SCOPE_AGENT);
          out[bb * 260 + 256] = -0.5f * (470.49652900079245f + xsq) + trj;
          out[bb * 260 + 257] = kl;
          out[bb * 260 + 258] = vfn;
          out[bb * 260 + 259] = jfn;
        }
      }
    }
  }
}

extern "C" void kernel_launch(void* const* d_in, const int* in_sizes, int n_in,
                              void* d_out, int out_size, void* d_ws, size_t ws_size,
                              hipStream_t stream) {
  (void)in_sizes; (void)n_in; (void)out_size; (void)ws_size;
  const float* x0 = (const float*)d_in[0];
  const float* W1 = (const float*)d_in[1];
  const float* b1 = (const float*)d_in[2];
  const float* wt = (const float*)d_in[3];
  const float* W2 = (const float*)d_in[4];
  const float* b2 = (const float*)d_in[5];
  const float* mu = (const float*)d_in[6];
  float* out = (float*)d_out;
  float* w = (float*)d_ws;

  float* Mm   = w;                  // 1048576
  float* Zz   = Mm + 1048576;       // 1048576
  float* cc   = Zz + 1048576;       // 1024
  float* bz   = cc + 1024;          // 1024
  float* ux   = bz + 1024;          // 8192
  float* hbuf = ux + 8192;          // 48*8192 = 393216
  float* scal = hbuf + 393216;      // 64
  unsigned* flags = (unsigned*)(scal + 64);  // 64 padded flags + done @1024

  precomp<<<dim3(553), dim3(256), 0, stream>>>(W1, W2, b2, x0, Mm, Zz, cc, bz,
                                               ux, scal, flags);
  ode_main<<<dim3(144), dim3(512), 0, stream>>>(x0, b1, wt, W2, b2, mu, out,
                                                Mm, Zz, cc, bz, ux, hbuf, scal,
                                                flags);
}

// Round 7
// 267.440 us; speedup vs baseline: 1.6878x; 1.6474x over previous
//
#include <hip/hip_runtime.h>
#include <math.h>

#define Hn 1024
#define Dn 256
#define Bn 8
#define DTf 0.125f

typedef __attribute__((ext_vector_type(4))) float f32x4;

constexpr float kA[6][5] = {
  {0.f, 0.f, 0.f, 0.f, 0.f},
  {1.0f/5.0f, 0.f, 0.f, 0.f, 0.f},
  {3.0f/40.0f, 9.0f/40.0f, 0.f, 0.f, 0.f},
  {44.0f/45.0f, -56.0f/15.0f, 32.0f/9.0f, 0.f, 0.f},
  {19372.0f/6561.0f, -25360.0f/2187.0f, 64448.0f/6561.0f, -212.0f/729.0f, 0.f},
  {9017.0f/3168.0f, -355.0f/33.0f, 46732.0f/5247.0f, 49.0f/176.0f, -5103.0f/18656.0f}
};
constexpr float kC[6] = {0.f, 0.2f, 0.3f, 0.8f, 8.0f/9.0f, 1.0f};
constexpr float kBW[6] = {35.0f/384.0f, 0.f, 500.0f/1113.0f, 125.0f/192.0f,
                          -2187.0f/6784.0f, 11.0f/84.0f};

__device__ __forceinline__ float fast_tanh(float x) {
  const float ax = fabsf(x);
  const float z = __expf(-2.0f * ax);
  const float t = (1.0f - z) * __builtin_amdgcn_rcpf(1.0f + z);
  return copysignf(t, x);
}

// ---------------- precompute ----------------
// wg 0..255: M = (W1^T W1).*(W2 W2^T); 256..511: Z = W2@W1; 512: scal/flags;
// 513..516: cc; 517..520: bz; 521..552: ux = x0@W1; 553..600: hbuf = 2.0f
__global__ __launch_bounds__(256) void precomp(
    const float* __restrict__ W1, const float* __restrict__ W2,
    const float* __restrict__ b2, const float* __restrict__ x0,
    float* __restrict__ Mm, float* __restrict__ Zz, float* __restrict__ cc,
    float* __restrict__ bz, float* __restrict__ ux, float* __restrict__ hbuf,
    float* __restrict__ scal, unsigned* __restrict__ flags) {
  __shared__ float sm[8704];
  const int tid = threadIdx.x;
  const int wg = blockIdx.x;
  if (wg < 256) {
    float* a1k  = sm;            // [32][64]
    float* a1l  = sm + 2048;     // [32][64]
    float* w2kT = sm + 4096;     // [32][72]
    float* w2lT = sm + 6400;     // [32][72]
    const int k0 = (wg & 15) * 64, l0 = (wg >> 4) * 64;
    const int kq = tid & 15, lq = tid >> 4;
    float g1[4][4] = {}, g2[4][4] = {};
    for (int dc = 0; dc < 8; dc++) {
      const int d0 = dc * 32;
      __syncthreads();
      for (int idx = tid; idx < 2048; idx += 256) {
        const int r1 = idx >> 6, c1 = idx & 63;
        a1k[r1 * 64 + c1] = W1[(d0 + r1) * Hn + k0 + c1];
        a1l[r1 * 64 + c1] = W1[(d0 + r1) * Hn + l0 + c1];
      }
      for (int idx = tid; idx < 2048; idx += 256) {
        const int r1 = idx >> 5, c1 = idx & 31;
        w2kT[c1 * 72 + r1] = W2[(k0 + r1) * Dn + d0 + c1];
        w2lT[c1 * 72 + r1] = W2[(l0 + r1) * Dn + d0 + c1];
      }
      __syncthreads();
      #pragma unroll 4
      for (int dd = 0; dd < 32; dd++) {
        const float4 ak = *(const float4*)&a1k[dd * 64 + kq * 4];
        const float4 al = *(const float4*)&a1l[dd * 64 + lq * 4];
        const float4 wk = *(const float4*)&w2kT[dd * 72 + kq * 4];
        const float4 wl = *(const float4*)&w2lT[dd * 72 + lq * 4];
        const float akv[4] = {ak.x, ak.y, ak.z, ak.w};
        const float alv[4] = {al.x, al.y, al.z, al.w};
        const float wkv[4] = {wk.x, wk.y, wk.z, wk.w};
        const float wlv[4] = {wl.x, wl.y, wl.z, wl.w};
        #pragma unroll
        for (int i = 0; i < 4; i++)
          #pragma unroll
          for (int j = 0; j < 4; j++) {
            g1[i][j] += akv[i] * alv[j];
            g2[i][j] += wkv[i] * wlv[j];
          }
      }
    }
    #pragma unroll
    for (int i = 0; i < 4; i++)
      #pragma unroll
      for (int j = 0; j < 4; j++)
        Mm[(k0 + kq * 4 + i) * Hn + l0 + lq * 4 + j] = g1[i][j] * g2[i][j];
  } else if (wg < 512) {
    float* w2lT = sm;            // [64][72]
    float* w1t  = sm + 4608;     // [64][64]
    const int bw = wg - 256;
    const int e0 = (bw & 15) * 64, l0 = (bw >> 4) * 64;
    const int eq = tid & 15, lq = tid >> 4;
    float acc[4][4] = {};
    for (int dc = 0; dc < 4; dc++) {
      const int d0 = dc * 64;
      __syncthreads();
      for (int idx = tid; idx < 4096; idx += 256) {
        const int r1 = idx >> 6, c1 = idx & 63;
        w2lT[c1 * 72 + r1] = W2[(l0 + r1) * Dn + d0 + c1];
        w1t[r1 * 64 + c1] = W1[(d0 + r1) * Hn + e0 + c1];
      }
      __syncthreads();
      #pragma unroll 4
      for (int dd = 0; dd < 64; dd++) {
        const float4 wv = *(const float4*)&w2lT[dd * 72 + lq * 4];
        const float4 xv = *(const float4*)&w1t[dd * 64 + eq * 4];
        const float wvv[4] = {wv.x, wv.y, wv.z, wv.w};
        const float xvv[4] = {xv.x, xv.y, xv.z, xv.w};
        #pragma unroll
        for (int i = 0; i < 4; i++)
          #pragma unroll
          for (int j = 0; j < 4; j++)
            acc[i][j] += wvv[i] * xvv[j];
      }
    }
    #pragma unroll
    for (int i = 0; i < 4; i++)
      #pragma unroll
      for (int j = 0; j < 4; j++)
        Zz[(l0 + lq * 4 + i) * Hn + e0 + eq * 4 + j] = acc[i][j];
  } else if (wg == 512) {
    if (tid < 64) scal[tid] = 0.f;
    if (tid == 0) flags[1024] = 0u;
  } else if (wg < 517) {
    const int k = (wg - 513) * 256 + tid;
    float s = 0.f;
    for (int d = 0; d < Dn; d++) s += W1[d * Hn + k] * W2[k * Dn + d];
    cc[k] = s;
  } else if (wg < 521) {
    const int e = (wg - 517) * 256 + tid;
    float s = 0.f;
    for (int d = 0; d < Dn; d++) s += b2[d] * W1[d * Hn + e];
    bz[e] = s;
  } else if (wg < 553) {
    const int idx = (wg - 521) * 256 + tid;   // ux[b][e] = x0 @ W1
    const int b = idx >> 10, e = idx & 1023;
    float s = 0.f;
    for (int d = 0; d < Dn; d++) s += x0[b * Dn + d] * W1[d * Hn + e];
    ux[b * Hn + e] = s;
  } else {
    // hbuf sentinel fill: 48 wgs x 8192 floats
    float* base = hbuf + (size_t)(wg - 553) * 8192;
    const f32x4 sent = {2.0f, 2.0f, 2.0f, 2.0f};
    for (int idx = tid; idx < 2048; idx += 256)
      *(f32x4*)&base[idx * 4] = sent;
  }
}

// ---------------- persistent main, data-as-flag ----------------
// wg 0..63: G (Z cols, publishes h)  wg 64..127: R (M)  wg 128..143: K (W2)
__global__ __launch_bounds__(512) void ode_main(
    const float* __restrict__ x0, const float* __restrict__ b1,
    const float* __restrict__ wt, const float* __restrict__ W2g,
    const float* __restrict__ b2, const float* __restrict__ mu,
    float* __restrict__ out,
    const float* __restrict__ Mm, const float* __restrict__ Zz,
    const float* __restrict__ cc, const float* __restrict__ bz,
    const float* __restrict__ ux, float* __restrict__ hbuf,
    float* __restrict__ scal, unsigned* __restrict__ flags) {
  __shared__ float Ms[16 * 1028];      // Mat slice [c][k]
  __shared__ float hsf[2][8 * 1028];   // h (or 1-h^2 for R), [ep][b][k]
  __shared__ float red[2][8][8][20];   // [ep][wv][cp][16]

  const int tid = threadIdx.x;
  const int wg = blockIdx.x;
  int role, cidx;
  if (wg < 64) { role = 0; cidx = wg; }
  else if (wg < 128) { role = 1; cidx = wg - 64; }
  else { role = 2; cidx = wg - 128; }
  const int wv = tid >> 6, lane = tid & 63;
  const int cp = lane & 7, ks = lane >> 3;
  const int b = tid >> 4, cl = tid & 15;    // epilogue mapping (tid<128)
  const int lh = lane >> 5, lc = lane & 31; // staging mapping

  float ubr = 0.f, xbr = 0.f;
  float b1c = 0.f, wtc = 0.f, bzc = 0.f, ccr = 0.f, b2c = 0.f, muc = 0.f;
  float gkr[6] = {}, kr[6] = {};
  float acc_a = 0.f, acc_b = 0.f;

  // ---- prologue ----
  if (role == 0) {
    if (tid < 128) {
      const int col = 16 * cidx + cl;
      b1c = b1[col]; wtc = wt[col]; bzc = bz[col];
      ubr = ux[b * Hn + col];
      const float h0 = fast_tanh(ubr + b1c);   // t = 0
      __hip_atomic_store(&hbuf[b * 1024 + col], h0, __ATOMIC_RELAXED,
                         __HIP_MEMORY_SCOPE_AGENT);  // fire & forget
    }
  } else if (role == 1) {
    if (tid < 128) ccr = cc[16 * cidx + cl];
  } else {
    if (tid < 128) {
      const int d = 16 * cidx + cl;
      xbr = x0[b * Dn + d];
      muc = mu[d]; b2c = b2[d];
      float v = xbr * xbr;
      v += __shfl_xor(v, 1, 64); v += __shfl_xor(v, 2, 64);
      v += __shfl_xor(v, 4, 64); v += __shfl_xor(v, 8, 64);
      if (cl == 0) atomicAdd(&scal[b * 8 + 4], v);
    }
  }

  // ---- stage Mat slice into LDS ([c][k]) ----
  {
    const float* msrc = (role == 0) ? Zz : (role == 1) ? Mm : W2g;
    const int mld = (role == 2) ? Dn : Hn;
    const int cb = 16 * cidx;
    for (int j = 0; j < 32; ++j) {
      const int idx = j * 512 + tid;
      const int l = idx >> 4, c = idx & 15;
      Ms[c * 1028 + l] = msrc[l * mld + cb + c];
    }
  }
  __syncthreads();

  int ep = 0;
  // ---- main loop ----
  for (int n = 0; n < 8; ++n) {
    #pragma unroll
    for (int i = 0; i < 6; ++i) {
      const int s = n * 6 + i;
      if (role == 0 && s == 47) break;    // G: stage 47 feeds nothing
      if (role == 1 && i == 1) continue;  // R: BW[1]==0, output unused

      // ---- poll + load own K-slice (data-as-flag, batched sc loads) ----
      const float* hb0 = hbuf + (size_t)s * 8192 + (size_t)lh * 1024 +
                         128 * wv + 4 * lc;
      const float* q0 = hb0;
      const float* q1 = hb0 + 2048;
      const float* q2 = hb0 + 4096;
      const float* q3 = hb0 + 6144;
      f32x4 v0, v1, v2, v3;
      while (true) {
        asm volatile(
            "global_load_dwordx4 %0, %4, off sc0 sc1\n\t"
            "global_load_dwordx4 %1, %5, off sc0 sc1\n\t"
            "global_load_dwordx4 %2, %6, off sc0 sc1\n\t"
            "global_load_dwordx4 %3, %7, off sc0 sc1\n\t"
            "s_waitcnt vmcnt(0)"
            : "=&v"(v0), "=&v"(v1), "=&v"(v2), "=&v"(v3)
            : "v"(q0), "v"(q1), "v"(q2), "v"(q3)
            : "memory");
        const int bad =
            (v0.x == 2.0f) | (v0.y == 2.0f) | (v0.z == 2.0f) | (v0.w == 2.0f) |
            (v1.x == 2.0f) | (v1.y == 2.0f) | (v1.z == 2.0f) | (v1.w == 2.0f) |
            (v2.x == 2.0f) | (v2.y == 2.0f) | (v2.z == 2.0f) | (v2.w == 2.0f) |
            (v3.x == 2.0f) | (v3.y == 2.0f) | (v3.z == 2.0f) | (v3.w == 2.0f);
        if (!__any(bad)) break;
        if (role == 0) __builtin_amdgcn_s_sleep(1);
        else           __builtin_amdgcn_s_sleep(8);
      }
      if (role == 1) {
        v0 = 1.0f - v0 * v0; v1 = 1.0f - v1 * v1;
        v2 = 1.0f - v2 * v2; v3 = 1.0f - v3 * v3;
      }
      {
        const int kofs = 128 * wv + 4 * lc;
        *(f32x4*)&hsf[ep][(0 + lh) * 1028 + kofs] = v0;
        *(f32x4*)&hsf[ep][(2 + lh) * 1028 + kofs] = v1;
        *(f32x4*)&hsf[ep][(4 + lh) * 1028 + kofs] = v2;
        *(f32x4*)&hsf[ep][(6 + lh) * 1028 + kofs] = v3;
      }

      // ---- matvec from LDS (wave-private K-slice) ----
      float av[16] = {};
      #pragma unroll
      for (int j = 0; j < 4; ++j) {
        const int kb = 128 * wv + 4 * ks + 32 * j;
        const f32x4 z0 = *(const f32x4*)&Ms[(2 * cp) * 1028 + kb];
        const f32x4 z1 = *(const f32x4*)&Ms[(2 * cp + 1) * 1028 + kb];
        #pragma unroll
        for (int bb = 0; bb < 8; ++bb) {
          const f32x4 hb = *(const f32x4*)&hsf[ep][bb * 1028 + kb];
          av[bb]     += z0.x * hb.x + z0.y * hb.y + z0.z * hb.z + z0.w * hb.w;
          av[8 + bb] += z1.x * hb.x + z1.y * hb.y + z1.z * hb.z + z1.w * hb.w;
        }
      }
      #pragma unroll
      for (int q = 0; q < 16; ++q) {
        av[q] += __shfl_xor(av[q], 8, 64);
        av[q] += __shfl_xor(av[q], 16, 64);
        av[q] += __shfl_xor(av[q], 32, 64);
      }
      if (ks == 0) {
        float* rp = &red[ep][wv][cp][0];
        #pragma unroll
        for (int q = 0; q < 16; ++q) rp[q] = av[q];
      }
      __syncthreads();   // red (and hsf for R's epilogue) complete

      // ---- epilogue (waves 0-1) ----
      if (tid < 128) {
        float r = 0.f;
        #pragma unroll
        for (int w = 0; w < 8; ++w)
          r += red[ep][w][cl >> 1][(cl & 1) * 8 + b];
        if (role == 0) {
          gkr[i] = r + bzc;
          float u;
          if (i == 5) {
            ubr += DTf * (kBW[0] * gkr[0] + kBW[2] * gkr[2] + kBW[3] * gkr[3] +
                          kBW[4] * gkr[4] + kBW[5] * gkr[5]);
            u = ubr + b1c + wtc * ((float)(n + 1) * DTf);
          } else {
            u = ubr + b1c + wtc * (((float)n + kC[i + 1]) * DTf);
            #pragma unroll
            for (int j2 = 0; j2 <= i; ++j2) u += DTf * kA[i + 1][j2] * gkr[j2];
          }
          const float hn2 = fast_tanh(u);
          __hip_atomic_store(
              &hbuf[(size_t)(s + 1) * 8192 + b * 1024 + 16 * cidx + cl], hn2,
              __ATOMIC_RELAXED, __HIP_MEMORY_SCOPE_AGENT);  // fire & forget
        } else if (role == 1) {
          const float sv = hsf[ep][b * 1028 + 16 * cidx + cl];
          float u1 = sv * r;        // -> jfn
          float u2 = sv * ccr;      // -> trJ
          u1 += __shfl_xor(u1, 1, 64); u2 += __shfl_xor(u2, 1, 64);
          u1 += __shfl_xor(u1, 2, 64); u2 += __shfl_xor(u2, 2, 64);
          u1 += __shfl_xor(u1, 4, 64); u2 += __shfl_xor(u2, 4, 64);
          u1 += __shfl_xor(u1, 8, 64); u2 += __shfl_xor(u2, 8, 64);
          if (cl == 0) {
            const float wgt = DTf * kBW[i];
            acc_a += -wgt * u2;   // dlogq = -trJ
            acc_b += wgt * u1;    // jfn
          }
        } else {
          const float kv = r + b2c;
          kr[i] = kv;
          float xi = xbr;
          #pragma unroll
          for (int j2 = 0; j2 < i; ++j2) xi += DTf * kA[i][j2] * kr[j2];
          float u1 = (xi - muc) * kv;   // -> kl
          float u2 = kv * kv;           // -> vfn
          u1 += __shfl_xor(u1, 1, 64); u2 += __shfl_xor(u2, 1, 64);
          u1 += __shfl_xor(u1, 2, 64); u2 += __shfl_xor(u2, 2, 64);
          u1 += __shfl_xor(u1, 4, 64); u2 += __shfl_xor(u2, 4, 64);
          u1 += __shfl_xor(u1, 8, 64); u2 += __shfl_xor(u2, 8, 64);
          if (cl == 0) {
            const float wgt = DTf * kBW[i];
            acc_a += wgt * u1;
            acc_b += wgt * u2;
          }
          if (i == 5)
            xbr += DTf * (kBW[0] * kr[0] + kBW[2] * kr[2] + kBW[3] * kr[3] +
                          kBW[4] * kr[4] + kBW[5] * kr[5]);
        }
      }
      ep ^= 1;
    }
  }

  // ---- finalize ----
  if (role == 1) {
    if (tid < 128 && cl == 0) {
      atomicAdd(&scal[b * 8 + 0], acc_a);
      atomicAdd(&scal[b * 8 + 3], acc_b);
    }
  } else if (role == 2) {
    if (tid < 128) out[b * 260 + 16 * cidx + cl] = xbr;
    if (tid < 128 && cl == 0) {
      atomicAdd(&scal[b * 8 + 1], acc_a);
      atomicAdd(&scal[b * 8 + 2], acc_b);
    }
  }
  if (role != 0) {
    asm volatile("s_waitcnt vmcnt(0)" ::: "memory");
    __syncthreads();
    if (tid == 0) {
      const unsigned old = __hip_atomic_fetch_add(&flags[1024], 1u,
                                                  __ATOMIC_RELAXED,
                                                  __HIP_MEMORY_SCOPE_AGENT);
      if (old == 79u) {   // last of 80 consumers writes the scalar outputs
        for (int bb = 0; bb < Bn; ++bb) {
          const float trj = __hip_atomic_load(&scal[bb * 8 + 0], __ATOMIC_RELAXED, __HIP_MEMORY_SCOPE_AGENT);
          const float kl  = __hip_atomic_load(&scal[bb * 8 + 1], __ATOMIC_RELAXED, __HIP_MEMORY_SCOPE_AGENT);
          const float vfn = __hip_atomic_load(&scal[bb * 8 + 2], __ATOMIC_RELAXED, __HIP_MEMORY_SCOPE_AGENT);
          const float jfn = __hip_atomic_load(&scal[bb * 8 + 3], __ATOMIC_RELAXED, __HIP_MEMORY_SCOPE_AGENT);
          const float xsq = __hip_atomic_load(&scal[bb * 8 + 4], __ATOMIC_RELAXED, __HIP_MEMORY_SCOPE_AGENT);
          out[bb * 260 + 256] = -0.5f * (470.49652900079245f + xsq) + trj;
          out[bb * 260 + 257] = kl;
          out[bb * 260 + 258] = vfn;
          out[bb * 260 + 259] = jfn;
        }
      }
    }
  }
}

extern "C" void kernel_launch(void* const* d_in, const int* in_sizes, int n_in,
                              void* d_out, int out_size, void* d_ws, size_t ws_size,
                              hipStream_t stream) {
  (void)in_sizes; (void)n_in; (void)out_size; (void)ws_size;
  const float* x0 = (const float*)d_in[0];
  const float* W1 = (const float*)d_in[1];
  const float* b1 = (const float*)d_in[2];
  const float* wt = (const float*)d_in[3];
  const float* W2 = (const float*)d_in[4];
  const float* b2 = (const float*)d_in[5];
  const float* mu = (const float*)d_in[6];
  float* out = (float*)d_out;
  float* w = (float*)d_ws;

  float* Mm   = w;                  // 1048576
  float* Zz   = Mm + 1048576;       // 1048576
  float* cc   = Zz + 1048576;       // 1024
  float* bz   = cc + 1024;          // 1024
  float* ux   = bz + 1024;          // 8192
  float* hbuf = ux + 8192;          // 48*8192 = 393216
  float* scal = hbuf + 393216;      // 64
  unsigned* flags = (unsigned*)(scal + 64);  // only [1024] used (done counter)

  precomp<<<dim3(601), dim3(256), 0, stream>>>(W1, W2, b2, x0, Mm, Zz, cc, bz,
                                               ux, hbuf, scal, flags);
  ode_main<<<dim3(144), dim3(512), 0, stream>>>(x0, b1, wt, W2, b2, mu, out,
                                                Mm, Zz, cc, bz, ux, hbuf, scal,
                                                flags);
}

// Round 8
// 250.277 us; speedup vs baseline: 1.8036x; 1.0686x over previous
//
#include <hip/hip_runtime.h>
#include <math.h>

#define Hn 1024
#define Dn 256
#define Bn 8
#define DTf 0.125f

typedef __attribute__((ext_vector_type(4))) float f32x4;

constexpr float kA[6][5] = {
  {0.f, 0.f, 0.f, 0.f, 0.f},
  {1.0f/5.0f, 0.f, 0.f, 0.f, 0.f},
  {3.0f/40.0f, 9.0f/40.0f, 0.f, 0.f, 0.f},
  {44.0f/45.0f, -56.0f/15.0f, 32.0f/9.0f, 0.f, 0.f},
  {19372.0f/6561.0f, -25360.0f/2187.0f, 64448.0f/6561.0f, -212.0f/729.0f, 0.f},
  {9017.0f/3168.0f, -355.0f/33.0f, 46732.0f/5247.0f, 49.0f/176.0f, -5103.0f/18656.0f}
};
constexpr float kC[6] = {0.f, 0.2f, 0.3f, 0.8f, 8.0f/9.0f, 1.0f};
constexpr float kBW[6] = {35.0f/384.0f, 0.f, 500.0f/1113.0f, 125.0f/192.0f,
                          -2187.0f/6784.0f, 11.0f/84.0f};

__device__ __forceinline__ float fast_tanh(float x) {
  const float ax = fabsf(x);
  const float z = __expf(-2.0f * ax);
  const float t = (1.0f - z) * __builtin_amdgcn_rcpf(1.0f + z);
  return copysignf(t, x);
}

// ---------------- precompute ----------------
// wg 0..255: M = (W1^T W1).*(W2 W2^T); 256..511: Z = W2@W1; 512: scal/flags;
// 513..516: cc; 517..520: bz; 521..552: ux = x0@W1; 553..600: hbuf = 2.0f
__global__ __launch_bounds__(256) void precomp(
    const float* __restrict__ W1, const float* __restrict__ W2,
    const float* __restrict__ b2, const float* __restrict__ x0,
    float* __restrict__ Mm, float* __restrict__ Zz, float* __restrict__ cc,
    float* __restrict__ bz, float* __restrict__ ux, float* __restrict__ hbuf,
    float* __restrict__ scal, unsigned* __restrict__ flags) {
  __shared__ float sm[8704];
  const int tid = threadIdx.x;
  const int wg = blockIdx.x;
  if (wg < 256) {
    float* a1k  = sm;            // [32][64]
    float* a1l  = sm + 2048;     // [32][64]
    float* w2kT = sm + 4096;     // [32][72]
    float* w2lT = sm + 6400;     // [32][72]
    const int k0 = (wg & 15) * 64, l0 = (wg >> 4) * 64;
    const int kq = tid & 15, lq = tid >> 4;
    float g1[4][4] = {}, g2[4][4] = {};
    for (int dc = 0; dc < 8; dc++) {
      const int d0 = dc * 32;
      __syncthreads();
      for (int idx = tid; idx < 2048; idx += 256) {
        const int r1 = idx >> 6, c1 = idx & 63;
        a1k[r1 * 64 + c1] = W1[(d0 + r1) * Hn + k0 + c1];
        a1l[r1 * 64 + c1] = W1[(d0 + r1) * Hn + l0 + c1];
      }
      for (int idx = tid; idx < 2048; idx += 256) {
        const int r1 = idx >> 5, c1 = idx & 31;
        w2kT[c1 * 72 + r1] = W2[(k0 + r1) * Dn + d0 + c1];
        w2lT[c1 * 72 + r1] = W2[(l0 + r1) * Dn + d0 + c1];
      }
      __syncthreads();
      #pragma unroll 4
      for (int dd = 0; dd < 32; dd++) {
        const float4 ak = *(const float4*)&a1k[dd * 64 + kq * 4];
        const float4 al = *(const float4*)&a1l[dd * 64 + lq * 4];
        const float4 wk = *(const float4*)&w2kT[dd * 72 + kq * 4];
        const float4 wl = *(const float4*)&w2lT[dd * 72 + lq * 4];
        const float akv[4] = {ak.x, ak.y, ak.z, ak.w};
        const float alv[4] = {al.x, al.y, al.z, al.w};
        const float wkv[4] = {wk.x, wk.y, wk.z, wk.w};
        const float wlv[4] = {wl.x, wl.y, wl.z, wl.w};
        #pragma unroll
        for (int i = 0; i < 4; i++)
          #pragma unroll
          for (int j = 0; j < 4; j++) {
            g1[i][j] += akv[i] * alv[j];
            g2[i][j] += wkv[i] * wlv[j];
          }
      }
    }
    #pragma unroll
    for (int i = 0; i < 4; i++)
      #pragma unroll
      for (int j = 0; j < 4; j++)
        Mm[(k0 + kq * 4 + i) * Hn + l0 + lq * 4 + j] = g1[i][j] * g2[i][j];
  } else if (wg < 512) {
    float* w2lT = sm;            // [64][72]
    float* w1t  = sm + 4608;     // [64][64]
    const int bw = wg - 256;
    const int e0 = (bw & 15) * 64, l0 = (bw >> 4) * 64;
    const int eq = tid & 15, lq = tid >> 4;
    float acc[4][4] = {};
    for (int dc = 0; dc < 4; dc++) {
      const int d0 = dc * 64;
      __syncthreads();
      for (int idx = tid; idx < 4096; idx += 256) {
        const int r1 = idx >> 6, c1 = idx & 63;
        w2lT[c1 * 72 + r1] = W2[(l0 + r1) * Dn + d0 + c1];
        w1t[r1 * 64 + c1] = W1[(d0 + r1) * Hn + e0 + c1];
      }
      __syncthreads();
      #pragma unroll 4
      for (int dd = 0; dd < 64; dd++) {
        const float4 wv = *(const float4*)&w2lT[dd * 72 + lq * 4];
        const float4 xv = *(const float4*)&w1t[dd * 64 + eq * 4];
        const float wvv[4] = {wv.x, wv.y, wv.z, wv.w};
        const float xvv[4] = {xv.x, xv.y, xv.z, xv.w};
        #pragma unroll
        for (int i = 0; i < 4; i++)
          #pragma unroll
          for (int j = 0; j < 4; j++)
            acc[i][j] += wvv[i] * xvv[j];
      }
    }
    #pragma unroll
    for (int i = 0; i < 4; i++)
      #pragma unroll
      for (int j = 0; j < 4; j++)
        Zz[(l0 + lq * 4 + i) * Hn + e0 + eq * 4 + j] = acc[i][j];
  } else if (wg == 512) {
    if (tid < 64) scal[tid] = 0.f;
    if (tid == 0) flags[1024] = 0u;
  } else if (wg < 517) {
    const int k = (wg - 513) * 256 + tid;
    float s = 0.f;
    for (int d = 0; d < Dn; d++) s += W1[d * Hn + k] * W2[k * Dn + d];
    cc[k] = s;
  } else if (wg < 521) {
    const int e = (wg - 517) * 256 + tid;
    float s = 0.f;
    for (int d = 0; d < Dn; d++) s += b2[d] * W1[d * Hn + e];
    bz[e] = s;
  } else if (wg < 553) {
    const int idx = (wg - 521) * 256 + tid;   // ux[b][e] = x0 @ W1
    const int b = idx >> 10, e = idx & 1023;
    float s = 0.f;
    for (int d = 0; d < Dn; d++) s += x0[b * Dn + d] * W1[d * Hn + e];
    ux[b * Hn + e] = s;
  } else {
    // hbuf sentinel fill: 48 wgs x 8192 floats
    float* base = hbuf + (size_t)(wg - 553) * 8192;
    const f32x4 sent = {2.0f, 2.0f, 2.0f, 2.0f};
    for (int idx = tid; idx < 2048; idx += 256)
      *(f32x4*)&base[idx * 4] = sent;
  }
}

// ---------------- persistent main, data-as-flag + probe/verify poll ----------------
// wg 0..63: G (Z cols, publishes h)  wg 64..127: R (M)  wg 128..143: K (W2)
__global__ __launch_bounds__(512) void ode_main(
    const float* __restrict__ x0, const float* __restrict__ b1,
    const float* __restrict__ wt, const float* __restrict__ W2g,
    const float* __restrict__ b2, const float* __restrict__ mu,
    float* __restrict__ out,
    const float* __restrict__ Mm, const float* __restrict__ Zz,
    const float* __restrict__ cc, const float* __restrict__ bz,
    const float* __restrict__ ux, float* __restrict__ hbuf,
    float* __restrict__ scal, unsigned* __restrict__ flags) {
  __shared__ float Ms[16 * 1028];      // Mat slice [c][k]
  __shared__ float hsf[2][8 * 1028];   // h (or 1-h^2 for R), [ep][b][k]
  __shared__ float red[2][8][8][20];   // [ep][wv][cp][16]

  const int tid = threadIdx.x;
  const int wg = blockIdx.x;
  int role, cidx;
  if (wg < 64) { role = 0; cidx = wg; }
  else if (wg < 128) { role = 1; cidx = wg - 64; }
  else { role = 2; cidx = wg - 128; }
  const int wv = tid >> 6, lane = tid & 63;
  const int cp = lane & 7, ks = lane >> 3;
  const int b = tid >> 4, cl = tid & 15;    // epilogue mapping (tid<128)
  const int lh = lane >> 5, lc = lane & 31; // staging mapping

  float ubr = 0.f, xbr = 0.f;
  float b1c = 0.f, wtc = 0.f, bzc = 0.f, ccr = 0.f, b2c = 0.f, muc = 0.f;
  float gkr[6] = {}, kr[6] = {};
  float acc_a = 0.f, acc_b = 0.f;

  // ---- prologue ----
  if (role == 0) {
    if (tid < 128) {
      const int col = 16 * cidx + cl;
      b1c = b1[col]; wtc = wt[col]; bzc = bz[col];
      ubr = ux[b * Hn + col];
      const float h0 = fast_tanh(ubr + b1c);   // t = 0
      __hip_atomic_store(&hbuf[b * 1024 + col], h0, __ATOMIC_RELAXED,
                         __HIP_MEMORY_SCOPE_AGENT);  // fire & forget
    }
  } else if (role == 1) {
    if (tid < 128) ccr = cc[16 * cidx + cl];
  } else {
    if (tid < 128) {
      const int d = 16 * cidx + cl;
      xbr = x0[b * Dn + d];
      muc = mu[d]; b2c = b2[d];
      float v = xbr * xbr;
      v += __shfl_xor(v, 1, 64); v += __shfl_xor(v, 2, 64);
      v += __shfl_xor(v, 4, 64); v += __shfl_xor(v, 8, 64);
      if (cl == 0) atomicAdd(&scal[b * 8 + 4], v);
    }
  }

  // ---- stage Mat slice into LDS ([c][k]) ----
  {
    const float* msrc = (role == 0) ? Zz : (role == 1) ? Mm : W2g;
    const int mld = (role == 2) ? Dn : Hn;
    const int cb = 16 * cidx;
    for (int j = 0; j < 32; ++j) {
      const int idx = j * 512 + tid;
      const int l = idx >> 4, c = idx & 15;
      Ms[c * 1028 + l] = msrc[l * mld + cb + c];
    }
  }
  __syncthreads();

  int ep = 0;
  // ---- main loop ----
  for (int n = 0; n < 8; ++n) {
    #pragma unroll
    for (int i = 0; i < 6; ++i) {
      const int s = n * 6 + i;
      if (role == 0 && s == 47) break;    // G: stage 47 feeds nothing
      if (role == 1 && i == 1) continue;  // R: BW[1]==0, output unused

      // ---- probe (1KB/wave) with backoff, then full verified load ----
      const float* hb0 = hbuf + (size_t)s * 8192 + (size_t)lh * 1024 +
                         128 * wv + 4 * lc;
      const float* q0 = hb0;
      const float* q1 = hb0 + 2048;
      const float* q2 = hb0 + 4096;
      const float* q3 = hb0 + 6144;
      f32x4 v0, v1, v2, v3;
      {
        int miss = 0;
        while (true) {
          asm volatile(
              "global_load_dwordx4 %0, %1, off sc0 sc1\n\t"
              "s_waitcnt vmcnt(0)"
              : "=&v"(v3) : "v"(q3) : "memory");
          const int bad3 = (v3.x == 2.0f) | (v3.y == 2.0f) |
                           (v3.z == 2.0f) | (v3.w == 2.0f);
          if (!__any(bad3)) break;
          if (role == 0) {
            if (miss > 2)       __builtin_amdgcn_s_sleep(4);
            else if (miss == 2) __builtin_amdgcn_s_sleep(2);
            else if (miss == 1) __builtin_amdgcn_s_sleep(1);
            // miss==0: immediate retry
          } else {
            if (miss > 0) __builtin_amdgcn_s_sleep(32);
            else          __builtin_amdgcn_s_sleep(8);
          }
          ++miss;
        }
        while (true) {
          asm volatile(
              "global_load_dwordx4 %0, %4, off sc0 sc1\n\t"
              "global_load_dwordx4 %1, %5, off sc0 sc1\n\t"
              "global_load_dwordx4 %2, %6, off sc0 sc1\n\t"
              "global_load_dwordx4 %3, %7, off sc0 sc1\n\t"
              "s_waitcnt vmcnt(0)"
              : "=&v"(v0), "=&v"(v1), "=&v"(v2), "=&v"(v3)
              : "v"(q0), "v"(q1), "v"(q2), "v"(q3)
              : "memory");
          const int bad =
              (v0.x == 2.0f) | (v0.y == 2.0f) | (v0.z == 2.0f) | (v0.w == 2.0f) |
              (v1.x == 2.0f) | (v1.y == 2.0f) | (v1.z == 2.0f) | (v1.w == 2.0f) |
              (v2.x == 2.0f) | (v2.y == 2.0f) | (v2.z == 2.0f) | (v2.w == 2.0f) |
              (v3.x == 2.0f) | (v3.y == 2.0f) | (v3.z == 2.0f) | (v3.w == 2.0f);
          if (!__any(bad)) break;
          __builtin_amdgcn_s_sleep(1);
        }
      }
      if (role == 1) {
        v0 = 1.0f - v0 * v0; v1 = 1.0f - v1 * v1;
        v2 = 1.0f - v2 * v2; v3 = 1.0f - v3 * v3;
      }
      {
        const int kofs = 128 * wv + 4 * lc;
        *(f32x4*)&hsf[ep][(0 + lh) * 1028 + kofs] = v0;
        *(f32x4*)&hsf[ep][(2 + lh) * 1028 + kofs] = v1;
        *(f32x4*)&hsf[ep][(4 + lh) * 1028 + kofs] = v2;
        *(f32x4*)&hsf[ep][(6 + lh) * 1028 + kofs] = v3;
      }

      // ---- matvec from LDS (wave-private K-slice) ----
      float av[16] = {};
      #pragma unroll
      for (int j = 0; j < 4; ++j) {
        const int kb = 128 * wv + 4 * ks + 32 * j;
        const f32x4 z0 = *(const f32x4*)&Ms[(2 * cp) * 1028 + kb];
        const f32x4 z1 = *(const f32x4*)&Ms[(2 * cp + 1) * 1028 + kb];
        #pragma unroll
        for (int bb = 0; bb < 8; ++bb) {
          const f32x4 hb = *(const f32x4*)&hsf[ep][bb * 1028 + kb];
          av[bb]     += z0.x * hb.x + z0.y * hb.y + z0.z * hb.z + z0.w * hb.w;
          av[8 + bb] += z1.x * hb.x + z1.y * hb.y + z1.z * hb.z + z1.w * hb.w;
        }
      }
      #pragma unroll
      for (int q = 0; q < 16; ++q) {
        av[q] += __shfl_xor(av[q], 8, 64);
        av[q] += __shfl_xor(av[q], 16, 64);
        av[q] += __shfl_xor(av[q], 32, 64);
      }
      if (ks == 0) {
        float* rp = &red[ep][wv][cp][0];
        #pragma unroll
        for (int q = 0; q < 16; ++q) rp[q] = av[q];
      }
      __syncthreads();   // red (and hsf for R's epilogue) complete

      // ---- epilogue (waves 0-1) ----
      if (tid < 128) {
        float r = 0.f;
        #pragma unroll
        for (int w = 0; w < 8; ++w)
          r += red[ep][w][cl >> 1][(cl & 1) * 8 + b];
        if (role == 0) {
          gkr[i] = r + bzc;
          float u;
          if (i == 5) {
            ubr += DTf * (kBW[0] * gkr[0] + kBW[2] * gkr[2] + kBW[3] * gkr[3] +
                          kBW[4] * gkr[4] + kBW[5] * gkr[5]);
            u = ubr + b1c + wtc * ((float)(n + 1) * DTf);
          } else {
            u = ubr + b1c + wtc * (((float)n + kC[i + 1]) * DTf);
            #pragma unroll
            for (int j2 = 0; j2 <= i; ++j2) u += DTf * kA[i + 1][j2] * gkr[j2];
          }
          const float hn2 = fast_tanh(u);
          __hip_atomic_store(
              &hbuf[(size_t)(s + 1) * 8192 + b * 1024 + 16 * cidx + cl], hn2,
              __ATOMIC_RELAXED, __HIP_MEMORY_SCOPE_AGENT);  // fire & forget
        } else if (role == 1) {
          const float sv = hsf[ep][b * 1028 + 16 * cidx + cl];
          float u1 = sv * r;        // -> jfn
          float u2 = sv * ccr;      // -> trJ
          u1 += __shfl_xor(u1, 1, 64); u2 += __shfl_xor(u2, 1, 64);
          u1 += __shfl_xor(u1, 2, 64); u2 += __shfl_xor(u2, 2, 64);
          u1 += __shfl_xor(u1, 4, 64); u2 += __shfl_xor(u2, 4, 64);
          u1 += __shfl_xor(u1, 8, 64); u2 += __shfl_xor(u2, 8, 64);
          if (cl == 0) {
            const float wgt = DTf * kBW[i];
            acc_a += -wgt * u2;   // dlogq = -trJ
            acc_b += wgt * u1;    // jfn
          }
        } else {
          const float kv = r + b2c;
          kr[i] = kv;
          float xi = xbr;
          #pragma unroll
          for (int j2 = 0; j2 < i; ++j2) xi += DTf * kA[i][j2] * kr[j2];
          float u1 = (xi - muc) * kv;   // -> kl
          float u2 = kv * kv;           // -> vfn
          u1 += __shfl_xor(u1, 1, 64); u2 += __shfl_xor(u2, 1, 64);
          u1 += __shfl_xor(u1, 2, 64); u2 += __shfl_xor(u2, 2, 64);
          u1 += __shfl_xor(u1, 4, 64); u2 += __shfl_xor(u2, 4, 64);
          u1 += __shfl_xor(u1, 8, 64); u2 += __shfl_xor(u2, 8, 64);
          if (cl == 0) {
            const float wgt = DTf * kBW[i];
            acc_a += wgt * u1;
            acc_b += wgt * u2;
          }
          if (i == 5)
            xbr += DTf * (kBW[0] * kr[0] + kBW[2] * kr[2] + kBW[3] * kr[3] +
                          kBW[4] * kr[4] + kBW[5] * kr[5]);
        }
      }
      ep ^= 1;
    }
  }

  // ---- finalize ----
  if (role == 1) {
    if (tid < 128 && cl == 0) {
      atomicAdd(&scal[b * 8 + 0], acc_a);
      atomicAdd(&scal[b * 8 + 3], acc_b);
    }
  } else if (role == 2) {
    if (tid < 128) out[b * 260 + 16 * cidx + cl] = xbr;
    if (tid < 128 && cl == 0) {
      atomicAdd(&scal[b * 8 + 1], acc_a);
      atomicAdd(&scal[b * 8 + 2], acc_b);
    }
  }
  if (role != 0) {
    asm volatile("s_waitcnt vmcnt(0)" ::: "memory");
    __syncthreads();
    if (tid == 0) {
      const unsigned old = __hip_atomic_fetch_add(&flags[1024], 1u,
                                                  __ATOMIC_RELAXED,
                                                  __HIP_MEMORY_SCOPE_AGENT);
      if (old == 79u) {   // last of 80 consumers writes the scalar outputs
        for (int bb = 0; bb < Bn; ++bb) {
          const float trj = __hip_atomic_load(&scal[bb * 8 + 0], __ATOMIC_RELAXED, __HIP_MEMORY_SCOPE_AGENT);
          const float kl  = __hip_atomic_load(&scal[bb * 8 + 1], __ATOMIC_RELAXED, __HIP_MEMORY_SCOPE_AGENT);
          const float vfn = __hip_atomic_load(&scal[bb * 8 + 2], __ATOMIC_RELAXED, __HIP_MEMORY_SCOPE_AGENT);
          const float jfn = __hip_atomic_load(&scal[bb * 8 + 3], __ATOMIC_RELAXED, __HIP_MEMORY_SCOPE_AGENT);
          const float xsq = __hip_atomic_load(&scal[bb * 8 + 4], __ATOMIC_RELAXED, __HIP_MEMORY_SCOPE_AGENT);
          out[bb * 260 + 256] = -0.5f * (470.49652900079245f + xsq) + trj;
          out[bb * 260 + 257] = kl;
          out[bb * 260 + 258] = vfn;
          out[bb * 260 + 259] = jfn;
        }
      }
    }
  }
}

extern "C" void kernel_launch(void* const* d_in, const int* in_sizes, int n_in,
                              void* d_out, int out_size, void* d_ws, size_t ws_size,
                              hipStream_t stream) {
  (void)in_sizes; (void)n_in; (void)out_size; (void)ws_size;
  const float* x0 = (const float*)d_in[0];
  const float* W1 = (const float*)d_in[1];
  const float* b1 = (const float*)d_in[2];
  const float* wt = (const float*)d_in[3];
  const float* W2 = (const float*)d_in[4];
  const float* b2 = (const float*)d_in[5];
  const float* mu = (const float*)d_in[6];
  float* out = (float*)d_out;
  float* w = (float*)d_ws;

  float* Mm   = w;                  // 1048576
  float* Zz   = Mm + 1048576;       // 1048576
  float* cc   = Zz + 1048576;       // 1024
  float* bz   = cc + 1024;          // 1024
  float* ux   = bz + 1024;          // 8192
  float* hbuf = ux + 8192;          // 48*8192 = 393216
  float* scal = hbuf + 393216;      // 64
  unsigned* flags = (unsigned*)(scal + 64);  // only [1024] used (done counter)

  precomp<<<dim3(601), dim3(256), 0, stream>>>(W1, W2, b2, x0, Mm, Zz, cc, bz,
                                               ux, hbuf, scal, flags);
  ode_main<<<dim3(144), dim3(512), 0, stream>>>(x0, b1, wt, W2, b2, mu, out,
                                                Mm, Zz, cc, bz, ux, hbuf, scal,
                                                flags);
}